// Round 1
// baseline (38217.477 us; speedup 1.0000x reference)
//
#include <hip/hip_runtime.h>
#include <math.h>

// Bidirectional LSTM, T=4096, B=1, I=H=1024, head -> 3 classes.
// Strategy: persistent kernel, weights register-resident, per-direction
// grid barrier per timestep, input projection overlapped with barrier wait.

#define T_SEQ 4096
#define ISZ   1024
#define HID   1024
#define NB_DIR 128      // blocks per direction
#define NB_TOT 256
#define NTHR   512
#define ROWS_PER_BLK 32 // 8 hidden units x 4 gates
#define UNITS_PER_BLK 8
#define KW 64           // weights per thread per matrix (K-chunk)
#define PAD_CHUNK 68    // 64 floats + 4 pad (bank-conflict break)

__device__ __forceinline__ float fast_sigmoid(float x) {
    return 1.0f / (1.0f + __expf(-x));
}
__device__ __forceinline__ float fast_tanh(float x) {
    // tanh(x) = 1 - 2/(e^{2x}+1); saturates correctly for |x| large.
    return 1.0f - 2.0f / (__expf(2.0f * x) + 1.0f);
}

__global__ __launch_bounds__(NTHR, 2)
void bilstm_persistent(const float* __restrict__ x,
                       const float* __restrict__ Wih_f, const float* __restrict__ Whh_f,
                       const float* __restrict__ bih_f, const float* __restrict__ bhh_f,
                       const float* __restrict__ Wih_b, const float* __restrict__ Whh_b,
                       const float* __restrict__ bih_b, const float* __restrict__ bhh_b,
                       unsigned int* ctr_base, float* hbuf /* [2 dir][2 buf][HID] */)
{
    const int tid = threadIdx.x;
    const int blk = blockIdx.x;
    const int dir = blk >> 7;          // 0 = fwd, 1 = bwd
    const int lb  = blk & 127;
    const int u0  = lb * UNITS_PER_BLK;
    const int r_local = tid >> 4;      // 0..31  (gate-row within block)
    const int kc  = tid & 15;          // k-chunk 0..15
    const int q   = r_local >> 3;      // gate index i,f,g,o
    const int uu  = r_local & 7;
    const int grow = q * HID + u0 + uu;

    const float* Wih = dir ? Wih_b : Wih_f;
    const float* Whh = dir ? Whh_b : Whh_f;
    const float* bih = dir ? bih_b : bih_f;
    const float* bhh = dir ? bhh_b : bhh_f;

    unsigned int* ctr = ctr_base + dir * 64;   // 256 B apart
    float* hb = hbuf + dir * 2 * HID;          // [2][HID]

    __shared__ float lds_h[16 * PAD_CHUNK];
    __shared__ float lds_x[16 * PAD_CHUNK];
    __shared__ float lds_g[ROWS_PER_BLK];
    __shared__ float lds_bias[ROWS_PER_BLK];

    // ---- one-time: weights into registers ----
    float wih[KW], whh[KW];
    {
        const float* pih = Wih + (size_t)grow * ISZ + kc * KW;
        const float* phh = Whh + (size_t)grow * HID + kc * KW;
        #pragma unroll
        for (int j = 0; j < KW; j += 4) {
            float4 a = *(const float4*)(pih + j);
            wih[j] = a.x; wih[j+1] = a.y; wih[j+2] = a.z; wih[j+3] = a.w;
            float4 b4 = *(const float4*)(phh + j);
            whh[j] = b4.x; whh[j+1] = b4.y; whh[j+2] = b4.z; whh[j+3] = b4.w;
        }
    }
    if (tid < ROWS_PER_BLK) {
        int qq = tid >> 3, u2 = tid & 7;
        int gr = qq * HID + u0 + u2;
        lds_bias[tid] = bih[gr] + bhh[gr];
    }

    float c_state = 0.0f;  // meaningful for tid < UNITS_PER_BLK

    // ---- stage x row for t=0, compute initial x-projection ----
    {
        int xrow = dir ? (T_SEQ - 1) : 0;
        const float* xp = x + (size_t)xrow * ISZ;
        int i0 = tid * 2;
        float2 v = *(const float2*)(xp + i0);
        *(float2*)&lds_x[(i0 >> 6) * PAD_CHUNK + (i0 & 63)] = v;
    }
    __syncthreads();
    float xacc = 0.0f;
    {
        const float* lx = lds_x + kc * PAD_CHUNK;
        #pragma unroll
        for (int j = 0; j < KW; j += 4) {
            float4 v = *(const float4*)(lx + j);
            xacc += wih[j]*v.x + wih[j+1]*v.y + wih[j+2]*v.z + wih[j+3]*v.w;
        }
    }

    bool dead = false;  // sticky barrier-bailout (avoid harness hang)

    for (int t = 0; t < T_SEQ; ++t) {
        float pre = xacc;

        if (t > 0) {
            // stage h(t-1) from global (agent-scope atomics: cross-XCD safe)
            float* hsrc = hb + ((t - 1) & 1) * HID;
            int i0 = tid * 2;
            float v0 = __hip_atomic_load(hsrc + i0,     __ATOMIC_RELAXED, __HIP_MEMORY_SCOPE_AGENT);
            float v1 = __hip_atomic_load(hsrc + i0 + 1, __ATOMIC_RELAXED, __HIP_MEMORY_SCOPE_AGENT);
            lds_h[(i0 >> 6) * PAD_CHUNK + (i0 & 63)]           = v0;
            lds_h[((i0 + 1) >> 6) * PAD_CHUNK + ((i0 + 1) & 63)] = v1;
            __syncthreads();
            const float* lh = lds_h + kc * PAD_CHUNK;
            #pragma unroll
            for (int j = 0; j < KW; j += 4) {
                float4 v = *(const float4*)(lh + j);
                pre += whh[j]*v.x + whh[j+1]*v.y + whh[j+2]*v.z + whh[j+3]*v.w;
            }
        }

        // reduce partial over the 16 k-chunk lanes (lanes differ in low 4 bits)
        pre += __shfl_xor(pre, 1);
        pre += __shfl_xor(pre, 2);
        pre += __shfl_xor(pre, 4);
        pre += __shfl_xor(pre, 8);
        if (kc == 0) lds_g[r_local] = pre + lds_bias[r_local];
        __syncthreads();

        // gate nonlinearity + state update (8 threads)
        if (tid < UNITS_PER_BLK) {
            float gi = lds_g[0 * 8 + tid];
            float gf = lds_g[1 * 8 + tid];
            float gg = lds_g[2 * 8 + tid];
            float go = lds_g[3 * 8 + tid];
            float si = fast_sigmoid(gi);
            float sf = fast_sigmoid(gf);
            float so = fast_sigmoid(go);
            float tg = fast_tanh(gg);
            c_state = sf * c_state + si * tg;
            float hval = so * fast_tanh(c_state);
            __hip_atomic_store(hb + (t & 1) * HID + u0 + tid, hval,
                               __ATOMIC_RELEASE, __HIP_MEMORY_SCOPE_AGENT);
        }
        __syncthreads();  // drain h stores (barrier implies vmcnt(0)) before arrival

        if (tid == 0) {
            __hip_atomic_fetch_add(ctr, 1u, __ATOMIC_ACQ_REL, __HIP_MEMORY_SCOPE_AGENT);
        }

        // ---- overlap window: project x[t+1] while others arrive ----
        if (t + 1 < T_SEQ) {
            int xrow = dir ? (T_SEQ - 2 - t) : (t + 1);
            const float* xp = x + (size_t)xrow * ISZ;
            int i0 = tid * 2;
            float2 v = *(const float2*)(xp + i0);
            *(float2*)&lds_x[(i0 >> 6) * PAD_CHUNK + (i0 & 63)] = v;
            __syncthreads();
            xacc = 0.0f;
            const float* lx = lds_x + kc * PAD_CHUNK;
            #pragma unroll
            for (int j = 0; j < KW; j += 4) {
                float4 v4 = *(const float4*)(lx + j);
                xacc += wih[j]*v4.x + wih[j+1]*v4.y + wih[j+2]*v4.z + wih[j+3]*v4.w;
            }
        }

        // ---- per-direction grid barrier ----
        if (t + 1 < T_SEQ) {
            if (tid == 0 && !dead) {
                unsigned int target = (unsigned int)(t + 1) * NB_DIR;
                long spins = 0;
                while (__hip_atomic_load(ctr, __ATOMIC_ACQUIRE, __HIP_MEMORY_SCOPE_AGENT) < target) {
                    if (++spins > (1L << 24)) { dead = true; break; }
                }
            }
            __syncthreads();
        }
    }
}

__global__ void head_kernel(const float* __restrict__ W_ho,
                            const float* __restrict__ b_ho,
                            const float* __restrict__ hbuf,
                            float* __restrict__ out)
{
    // final h is in buffer index (T_SEQ-1)&1 == 1 for both directions
    const float* hf = hbuf + 1 * HID;            // dir 0, buf 1
    const float* hbk = hbuf + 2 * HID + 1 * HID; // dir 1, buf 1
    __shared__ float r0[4], r1[4], r2[4];
    int tid = threadIdx.x;  // 256 threads
    float p0 = 0.f, p1 = 0.f, p2 = 0.f;
    for (int i = tid; i < 2 * HID; i += 256) {
        float hv = (i < HID) ? hf[i] : hbk[i - HID];
        p0 += W_ho[0 * 2 * HID + i] * hv;
        p1 += W_ho[1 * 2 * HID + i] * hv;
        p2 += W_ho[2 * 2 * HID + i] * hv;
    }
    #pragma unroll
    for (int m = 1; m < 64; m <<= 1) {
        p0 += __shfl_xor(p0, m);
        p1 += __shfl_xor(p1, m);
        p2 += __shfl_xor(p2, m);
    }
    int w = tid >> 6;
    if ((tid & 63) == 0) { r0[w] = p0; r1[w] = p1; r2[w] = p2; }
    __syncthreads();
    if (tid == 0) {
        out[0] = b_ho[0] + r0[0] + r0[1] + r0[2] + r0[3];
        out[1] = b_ho[1] + r1[0] + r1[1] + r1[2] + r1[3];
        out[2] = b_ho[2] + r2[0] + r2[1] + r2[2] + r2[3];
    }
}

extern "C" void kernel_launch(void* const* d_in, const int* in_sizes, int n_in,
                              void* d_out, int out_size, void* d_ws, size_t ws_size,
                              hipStream_t stream) {
    const float* x     = (const float*)d_in[0];
    const float* Wih_f = (const float*)d_in[1];
    const float* Whh_f = (const float*)d_in[2];
    const float* bih_f = (const float*)d_in[3];
    const float* bhh_f = (const float*)d_in[4];
    const float* Wih_b = (const float*)d_in[5];
    const float* Whh_b = (const float*)d_in[6];
    const float* bih_b = (const float*)d_in[7];
    const float* bhh_b = (const float*)d_in[8];
    const float* W_ho  = (const float*)d_in[9];
    const float* b_ho  = (const float*)d_in[10];

    unsigned int* ctr = (unsigned int*)d_ws;                    // 512 B (2 ctrs, 256B apart)
    float* hbuf = (float*)((char*)d_ws + 512);                  // 2*2*1024 floats

    // reset barrier counters every call (ws is never re-poisoned between replays)
    hipMemsetAsync(d_ws, 0, 512, stream);

    bilstm_persistent<<<NB_TOT, NTHR, 0, stream>>>(
        x, Wih_f, Whh_f, bih_f, bhh_f, Wih_b, Whh_b, bih_b, bhh_b, ctr, hbuf);

    head_kernel<<<1, 256, 0, stream>>>(W_ho, b_ho, hbuf, (float*)d_out);
}

// Round 2
// 8955.045 us; speedup vs baseline: 4.2677x; 4.2677x over previous
//
#include <hip/hip_runtime.h>
#include <stdint.h>
#include <math.h>

// Bidirectional LSTM, T=4096, B=1, I=H=1024, head -> 3 classes.
// R2: register-pinned weights (asm pin defeats compiler re-load),
//     barrier-free dataflow sync via (epoch<<32 | h-bits) packed u64 atomics.

#define T_SEQ 4096
#define ISZ   1024
#define HID   1024
#define NB_DIR 128
#define NB_TOT 256
#define NTHR   512
#define ROWS_PER_BLK 32   // 8 hidden units x 4 gates
#define UNITS_PER_BLK 8
#define KW 64             // weights per thread per matrix
#define PAD_CHUNK 68      // 64 floats + 4 pad (bank-conflict break)

typedef unsigned long long u64;

__device__ __forceinline__ float fast_sigmoid(float x) {
    return 1.0f / (1.0f + __expf(-x));
}
__device__ __forceinline__ float fast_tanh(float x) {
    return 1.0f - 2.0f / (__expf(2.0f * x) + 1.0f);
}

__global__ __launch_bounds__(NTHR, 2)
void bilstm_persistent(const float* __restrict__ x,
                       const float* __restrict__ Wih_f, const float* __restrict__ Whh_f,
                       const float* __restrict__ bih_f, const float* __restrict__ bhh_f,
                       const float* __restrict__ Wih_b, const float* __restrict__ Whh_b,
                       const float* __restrict__ bih_b, const float* __restrict__ bhh_b,
                       u64* hpack /* [2 dir][2 buf][HID] packed (tag<<32)|h */)
{
    const int tid = threadIdx.x;
    const int blk = blockIdx.x;
    const int dir = blk >> 7;          // 0 = fwd, 1 = bwd
    const int lb  = blk & 127;
    const int u0  = lb * UNITS_PER_BLK;
    const int r_local = tid >> 4;      // 0..31 gate-row within block
    const int kc  = tid & 15;          // k-chunk 0..15
    const int q   = r_local >> 3;      // gate index i,f,g,o
    const int uu  = r_local & 7;
    const int grow = q * HID + u0 + uu;

    const float* Wih = dir ? Wih_b : Wih_f;
    const float* Whh = dir ? Whh_b : Whh_f;
    const float* bih = dir ? bih_b : bih_f;
    const float* bhh = dir ? bhh_b : bhh_f;

    u64* hp = hpack + (size_t)dir * 2 * HID;   // [2 buf][HID]

    __shared__ float lds_h[16 * PAD_CHUNK];
    __shared__ float lds_x[16 * PAD_CHUNK];
    __shared__ float lds_g[ROWS_PER_BLK];
    __shared__ float lds_bias[ROWS_PER_BLK];

    // ---- one-time: weights into registers ----
    float wih[KW], whh[KW];
    {
        const float* pih = Wih + (size_t)grow * ISZ + kc * KW;
        const float* phh = Whh + (size_t)grow * HID + kc * KW;
        #pragma unroll
        for (int j = 0; j < KW; j += 4) {
            float4 a = *(const float4*)(pih + j);
            wih[j] = a.x; wih[j+1] = a.y; wih[j+2] = a.z; wih[j+3] = a.w;
            float4 b4 = *(const float4*)(phh + j);
            whh[j] = b4.x; whh[j+1] = b4.y; whh[j+2] = b4.z; whh[j+3] = b4.w;
        }
    }
    // Pin: make values opaque so the compiler cannot re-load from global
    // inside the t-loop (R1 showed VGPR=84 -> weights were being re-streamed).
    #pragma unroll
    for (int j = 0; j < KW; ++j) {
        asm volatile("" : "+v"(wih[j]));
        asm volatile("" : "+v"(whh[j]));
    }

    if (tid < ROWS_PER_BLK) {
        int qq = tid >> 3, u2 = tid & 7;
        int gr = qq * HID + u0 + u2;
        lds_bias[tid] = bih[gr] + bhh[gr];
    }

    float c_state = 0.0f;  // meaningful for tid < UNITS_PER_BLK

    // ---- stage x row for t=0, compute initial x-projection ----
    {
        int xrow = dir ? (T_SEQ - 1) : 0;
        const float* xp = x + (size_t)xrow * ISZ;
        int i0 = tid * 2;
        float2 v = *(const float2*)(xp + i0);
        *(float2*)&lds_x[(i0 >> 6) * PAD_CHUNK + (i0 & 63)] = v;
    }
    __syncthreads();
    float xacc = 0.0f;
    {
        const float* lx = lds_x + kc * PAD_CHUNK;
        #pragma unroll
        for (int j = 0; j < KW; j += 4) {
            float4 v = *(const float4*)(lx + j);
            xacc += wih[j]*v.x + wih[j+1]*v.y + wih[j+2]*v.z + wih[j+3]*v.w;
        }
    }

    bool dead = false;  // sticky poll-bailout (avoid harness hang if not co-resident)

    for (int t = 0; t < T_SEQ; ++t) {
        float pre = xacc;

        if (t > 0) {
            // Dataflow: poll the two packed (tag,h) words this thread stages.
            u64* src = hp + ((size_t)((t - 1) & 1)) * HID;
            const int pi = tid * 2;
            u64 e0 = 0, e1 = 0;
            if (!dead) {
                int sp = 0;
                while (((e0 = __hip_atomic_load(src + pi, __ATOMIC_RELAXED,
                                                __HIP_MEMORY_SCOPE_AGENT)) >> 32)
                       != (unsigned)t) {
                    if (++sp > (1 << 21)) { dead = true; break; }
                }
                sp = 0;
                if (!dead) {
                    while (((e1 = __hip_atomic_load(src + pi + 1, __ATOMIC_RELAXED,
                                                    __HIP_MEMORY_SCOPE_AGENT)) >> 32)
                           != (unsigned)t) {
                        if (++sp > (1 << 21)) { dead = true; break; }
                    }
                }
            }
            lds_h[(pi >> 6) * PAD_CHUNK + (pi & 63)] =
                __uint_as_float((unsigned)(e0 & 0xffffffffu));
            lds_h[((pi + 1) >> 6) * PAD_CHUNK + ((pi + 1) & 63)] =
                __uint_as_float((unsigned)(e1 & 0xffffffffu));
            __syncthreads();
            const float* lh = lds_h + kc * PAD_CHUNK;
            #pragma unroll
            for (int j = 0; j < KW; j += 4) {
                float4 v = *(const float4*)(lh + j);
                pre += whh[j]*v.x + whh[j+1]*v.y + whh[j+2]*v.z + whh[j+3]*v.w;
            }
        }

        // reduce partials over the 16 k-chunk lanes
        pre += __shfl_xor(pre, 1);
        pre += __shfl_xor(pre, 2);
        pre += __shfl_xor(pre, 4);
        pre += __shfl_xor(pre, 8);
        if (kc == 0) lds_g[r_local] = pre + lds_bias[r_local];
        __syncthreads();

        // gate nonlinearity + state update + packed publish (8 threads)
        if (tid < UNITS_PER_BLK) {
            float gi = lds_g[0 * 8 + tid];
            float gf = lds_g[1 * 8 + tid];
            float gg = lds_g[2 * 8 + tid];
            float go = lds_g[3 * 8 + tid];
            float si = fast_sigmoid(gi);
            float sf = fast_sigmoid(gf);
            float so = fast_sigmoid(go);
            float tg = fast_tanh(gg);
            c_state = sf * c_state + si * tg;
            float hval = so * fast_tanh(c_state);
            u64 pk = ((u64)(unsigned)(t + 1) << 32) | (u64)__float_as_uint(hval);
            __hip_atomic_store(hp + ((size_t)(t & 1)) * HID + u0 + tid, pk,
                               __ATOMIC_RELAXED, __HIP_MEMORY_SCOPE_AGENT);
        }

        // ---- overlap: project x[t+1] while stores propagate ----
        if (t + 1 < T_SEQ) {
            int xrow = dir ? (T_SEQ - 2 - t) : (t + 1);
            const float* xp = x + (size_t)xrow * ISZ;
            int i0 = tid * 2;
            float2 v = *(const float2*)(xp + i0);
            *(float2*)&lds_x[(i0 >> 6) * PAD_CHUNK + (i0 & 63)] = v;
            __syncthreads();
            xacc = 0.0f;
            const float* lx = lds_x + kc * PAD_CHUNK;
            #pragma unroll
            for (int j = 0; j < KW; j += 4) {
                float4 v4 = *(const float4*)(lx + j);
                xacc += wih[j]*v4.x + wih[j+1]*v4.y + wih[j+2]*v4.z + wih[j+3]*v4.w;
            }
        }
    }
}

__global__ void head_kernel(const float* __restrict__ W_ho,
                            const float* __restrict__ b_ho,
                            const u64* __restrict__ hpack,
                            float* __restrict__ out)
{
    // final h for both dirs is in buf index (T_SEQ-1)&1 == 1
    const u64* hf  = hpack + 1 * HID;            // dir 0, buf 1
    const u64* hbk = hpack + 2 * HID + 1 * HID;  // dir 1, buf 1
    __shared__ float r0[4], r1[4], r2[4];
    int tid = threadIdx.x;  // 256 threads
    float p0 = 0.f, p1 = 0.f, p2 = 0.f;
    for (int i = tid; i < 2 * HID; i += 256) {
        u64 e = (i < HID) ? hf[i] : hbk[i - HID];
        float hv = __uint_as_float((unsigned)(e & 0xffffffffu));
        p0 += W_ho[0 * 2 * HID + i] * hv;
        p1 += W_ho[1 * 2 * HID + i] * hv;
        p2 += W_ho[2 * 2 * HID + i] * hv;
    }
    #pragma unroll
    for (int m = 1; m < 64; m <<= 1) {
        p0 += __shfl_xor(p0, m);
        p1 += __shfl_xor(p1, m);
        p2 += __shfl_xor(p2, m);
    }
    int w = tid >> 6;
    if ((tid & 63) == 0) { r0[w] = p0; r1[w] = p1; r2[w] = p2; }
    __syncthreads();
    if (tid == 0) {
        out[0] = b_ho[0] + r0[0] + r0[1] + r0[2] + r0[3];
        out[1] = b_ho[1] + r1[0] + r1[1] + r1[2] + r1[3];
        out[2] = b_ho[2] + r2[0] + r2[1] + r2[2] + r2[3];
    }
}

extern "C" void kernel_launch(void* const* d_in, const int* in_sizes, int n_in,
                              void* d_out, int out_size, void* d_ws, size_t ws_size,
                              hipStream_t stream) {
    const float* x     = (const float*)d_in[0];
    const float* Wih_f = (const float*)d_in[1];
    const float* Whh_f = (const float*)d_in[2];
    const float* bih_f = (const float*)d_in[3];
    const float* bhh_f = (const float*)d_in[4];
    const float* Wih_b = (const float*)d_in[5];
    const float* Whh_b = (const float*)d_in[6];
    const float* bih_b = (const float*)d_in[7];
    const float* bhh_b = (const float*)d_in[8];
    const float* W_ho  = (const float*)d_in[9];
    const float* b_ho  = (const float*)d_in[10];

    u64* hpack = (u64*)d_ws;   // [2][2][1024] packed words = 32 KB

    // zero tags every call (ws poisoned once, never re-poisoned between replays)
    hipMemsetAsync(d_ws, 0, 2 * 2 * HID * sizeof(u64), stream);

    bilstm_persistent<<<NB_TOT, NTHR, 0, stream>>>(
        x, Wih_f, Whh_f, bih_f, bhh_f, Wih_b, Whh_b, bih_b, bhh_b, hpack);

    head_kernel<<<1, 256, 0, stream>>>(W_ho, b_ho, hpack, (float*)d_out);
}

// Round 3
// 8397.408 us; speedup vs baseline: 4.5511x; 1.0664x over previous
//
#include <hip/hip_runtime.h>
#include <stdint.h>

// Bidirectional LSTM T=4096, B=1, I=H=1024 -> 3 classes.
// R3: Phase 1 GEMM precomputes xg = x*Wih^T + bias (all t, both dirs) into ws.
//     Phase 2 persistent recurrence holds only Whh in regs (64 f/thread),
//     1 unit per wave (gates via intra-wave shfl), 1 barrier/step,
//     packed (epoch|h) u64 dataflow sync, xg prefetched 1 step ahead.

#define T_SEQ 4096
#define ISZ   1024
#define HID   1024
#define G4H   4096
#define NB_DIR 128
#define NB_TOT 256
#define NTHR  512
#define PAD   68

typedef unsigned long long u64;

__device__ __forceinline__ float fast_sigmoid(float x) {
    return 1.0f / (1.0f + __expf(-x));
}
__device__ __forceinline__ float fast_tanh(float x) {
    return 1.0f - 2.0f / (__expf(2.0f * x) + 1.0f);
}

// ---------------- Phase 1: xg[dir][t][g] = dot(x[row(t)], Wih[g]) + bih[g] + bhh[g]
#define GM 64
#define GN 64
#define GK 32

__global__ __launch_bounds__(256)
void xproj_gemm(const float* __restrict__ x,
                const float* __restrict__ Wih_f, const float* __restrict__ bih_f,
                const float* __restrict__ bhh_f,
                const float* __restrict__ Wih_b, const float* __restrict__ bih_b,
                const float* __restrict__ bhh_b,
                float* __restrict__ xg)
{
    const int dir = blockIdx.z;
    const float* Wih = dir ? Wih_b : Wih_f;
    const float* bih = dir ? bih_b : bih_f;
    const float* bhh = dir ? bhh_b : bhh_f;
    const int m0 = blockIdx.y * GM;   // t-tile
    const int n0 = blockIdx.x * GN;   // gate-row tile
    const int tid = threadIdx.x;
    const int ms = tid >> 2;          // 0..63 staging row
    const int kq = tid & 3;           // 0..3 staging k-quarter
    const int tm = tid >> 4;          // 0..15 micro-tile row group
    const int tn = tid & 15;          // 0..15 micro-tile col group

    __shared__ float As[GK][GM + 4];
    __shared__ float Bs[GK][GN + 4];

    float acc[4][4] = {};

    const int mrow = m0 + ms;
    const int xrow = dir ? (T_SEQ - 1 - mrow) : mrow;
    const float* ap = x + (size_t)xrow * ISZ + kq * 8;
    const float* bp = Wih + (size_t)(n0 + ms) * ISZ + kq * 8;

    for (int k0 = 0; k0 < ISZ; k0 += GK) {
        float4 a0 = *(const float4*)(ap + k0);
        float4 a1 = *(const float4*)(ap + k0 + 4);
        float4 b0 = *(const float4*)(bp + k0);
        float4 b1 = *(const float4*)(bp + k0 + 4);
        __syncthreads();  // protect LDS from previous panel's readers
        const int kb = kq * 8;
        As[kb+0][ms]=a0.x; As[kb+1][ms]=a0.y; As[kb+2][ms]=a0.z; As[kb+3][ms]=a0.w;
        As[kb+4][ms]=a1.x; As[kb+5][ms]=a1.y; As[kb+6][ms]=a1.z; As[kb+7][ms]=a1.w;
        Bs[kb+0][ms]=b0.x; Bs[kb+1][ms]=b0.y; Bs[kb+2][ms]=b0.z; Bs[kb+3][ms]=b0.w;
        Bs[kb+4][ms]=b1.x; Bs[kb+5][ms]=b1.y; Bs[kb+6][ms]=b1.z; Bs[kb+7][ms]=b1.w;
        __syncthreads();
        #pragma unroll
        for (int k = 0; k < GK; ++k) {
            float4 av = *(const float4*)&As[k][tm * 4];
            float4 bv = *(const float4*)&Bs[k][tn * 4];
            acc[0][0] += av.x*bv.x; acc[0][1] += av.x*bv.y; acc[0][2] += av.x*bv.z; acc[0][3] += av.x*bv.w;
            acc[1][0] += av.y*bv.x; acc[1][1] += av.y*bv.y; acc[1][2] += av.y*bv.z; acc[1][3] += av.y*bv.w;
            acc[2][0] += av.z*bv.x; acc[2][1] += av.z*bv.y; acc[2][2] += av.z*bv.z; acc[2][3] += av.z*bv.w;
            acc[3][0] += av.w*bv.x; acc[3][1] += av.w*bv.y; acc[3][2] += av.w*bv.z; acc[3][3] += av.w*bv.w;
        }
    }

    const int gc = n0 + tn * 4;
    float4 bb1 = *(const float4*)(bih + gc);
    float4 bb2 = *(const float4*)(bhh + gc);
    float bx = bb1.x + bb2.x, by = bb1.y + bb2.y, bz = bb1.z + bb2.z, bw = bb1.w + bb2.w;
    float* op = xg + ((size_t)dir << 24) + (size_t)(m0 + tm * 4) * G4H + gc;
    #pragma unroll
    for (int i = 0; i < 4; ++i) {
        float4 v;
        v.x = acc[i][0] + bx; v.y = acc[i][1] + by;
        v.z = acc[i][2] + bz; v.w = acc[i][3] + bw;
        *(float4*)(op + (size_t)i * G4H) = v;
    }
}

// ---------------- Phase 2: persistent recurrence (Whh only)
__global__ __launch_bounds__(NTHR, 2)
void bilstm_rec(const float* __restrict__ xg,
                const float* __restrict__ Whh_f, const float* __restrict__ Whh_b,
                u64* hpack)
{
    const int tid = threadIdx.x;
    const int blk = blockIdx.x;
    const int dir = blk >> 7;
    const int lb  = blk & 127;
    const int u0  = lb * 8;
    const int w   = tid >> 6;        // wave 0..7 -> unit u0+w
    const int lane = tid & 63;
    const int q   = lane >> 4;       // gate 0..3 (i,f,g,o)
    const int kc  = lane & 15;       // k-chunk
    const int grow = q * HID + u0 + w;

    const float* Whh = dir ? Whh_b : Whh_f;
    const float* xgd = xg + ((size_t)dir << 24);
    u64* hp = hpack + (size_t)dir * 2 * HID;

    __shared__ float lds_h[2][16 * PAD];

    // one-time: Whh row-chunk into registers (64 floats)
    float whh[64];
    {
        const float* phh = Whh + (size_t)grow * HID + kc * 64;
        #pragma unroll
        for (int j = 0; j < 64; j += 4) {
            float4 v = *(const float4*)(phh + j);
            whh[j] = v.x; whh[j+1] = v.y; whh[j+2] = v.z; whh[j+3] = v.w;
        }
    }
    #pragma unroll
    for (int j = 0; j < 64; ++j) asm volatile("" : "+v"(whh[j]));

    float c_state = 0.0f;            // lane 0 of each wave
    float xgv = 0.0f;
    if (kc == 0) xgv = xgd[grow];    // t=0 row
    asm volatile("" : "+v"(xgv));

    bool dead = false;

    for (int t = 0; t < T_SEQ; ++t) {
        float pre = 0.0f;

        if (t > 0) {
            const int b = (t - 1) & 1;
            u64* src = hp + (size_t)b * HID;
            const int pi = tid * 2;
            u64 e0 = 0, e1 = 0;
            if (!dead) {
                int sp = 0;
                while (((e0 = __hip_atomic_load(src + pi, __ATOMIC_RELAXED,
                                                __HIP_MEMORY_SCOPE_AGENT)) >> 32)
                       != (unsigned)t) {
                    if (++sp > (1 << 21)) { dead = true; break; }
                }
                sp = 0;
                if (!dead) {
                    while (((e1 = __hip_atomic_load(src + pi + 1, __ATOMIC_RELAXED,
                                                    __HIP_MEMORY_SCOPE_AGENT)) >> 32)
                           != (unsigned)t) {
                        if (++sp > (1 << 21)) { dead = true; break; }
                    }
                }
            }
            float2 hv;
            hv.x = __uint_as_float((unsigned)(e0 & 0xffffffffu));
            hv.y = __uint_as_float((unsigned)(e1 & 0xffffffffu));
            *(float2*)&lds_h[b][(pi >> 6) * PAD + (pi & 63)] = hv;
            __syncthreads();
            const float* lh = &lds_h[b][kc * PAD];
            #pragma unroll
            for (int j = 0; j < 16; ++j) {
                float4 v = *(const float4*)(lh + j * 4);
                pre += whh[j*4+0]*v.x + whh[j*4+1]*v.y + whh[j*4+2]*v.z + whh[j*4+3]*v.w;
            }
        }

        // reduce over the 16 k-chunk lanes (low 4 lane bits)
        pre += __shfl_xor(pre, 1);
        pre += __shfl_xor(pre, 2);
        pre += __shfl_xor(pre, 4);
        pre += __shfl_xor(pre, 8);

        float pg = pre + xgv;        // valid at lanes 0,16,32,48 (kc==0)

        // gather the 4 gates of this wave's unit to lane 0
        float pf_g = __shfl(pg, 16);
        float pg_g = __shfl(pg, 32);
        float po_g = __shfl(pg, 48);

        if (lane == 0) {
            float si = fast_sigmoid(pg);
            float sf = fast_sigmoid(pf_g);
            float tg = fast_tanh(pg_g);
            float so = fast_sigmoid(po_g);
            c_state = sf * c_state + si * tg;
            float hval = so * fast_tanh(c_state);
            u64 pk = ((u64)(unsigned)(t + 1) << 32) | (u64)__float_as_uint(hval);
            __hip_atomic_store(hp + (size_t)(t & 1) * HID + u0 + w, pk,
                               __ATOMIC_RELAXED, __HIP_MEMORY_SCOPE_AGENT);
        }

        // prefetch next xg row (L3-resident; hides under next poll window)
        if (t + 1 < T_SEQ) {
            if (kc == 0) {
                xgv = xgd[(size_t)(t + 1) * G4H + grow];
                asm volatile("" : "+v"(xgv));
            }
        }
    }
}

// ---------------- head
__global__ void head_kernel(const float* __restrict__ W_ho,
                            const float* __restrict__ b_ho,
                            const u64* __restrict__ hpack,
                            float* __restrict__ out)
{
    const u64* hf  = hpack + 1 * HID;            // dir0 buf1
    const u64* hbk = hpack + 2 * HID + 1 * HID;  // dir1 buf1
    __shared__ float r0[4], r1[4], r2[4];
    int tid = threadIdx.x;  // 256
    float p0 = 0.f, p1 = 0.f, p2 = 0.f;
    for (int i = tid; i < 2 * HID; i += 256) {
        u64 e = (i < HID) ? hf[i] : hbk[i - HID];
        float hv = __uint_as_float((unsigned)(e & 0xffffffffu));
        p0 += W_ho[0 * 2 * HID + i] * hv;
        p1 += W_ho[1 * 2 * HID + i] * hv;
        p2 += W_ho[2 * 2 * HID + i] * hv;
    }
    #pragma unroll
    for (int m = 1; m < 64; m <<= 1) {
        p0 += __shfl_xor(p0, m);
        p1 += __shfl_xor(p1, m);
        p2 += __shfl_xor(p2, m);
    }
    int w = tid >> 6;
    if ((tid & 63) == 0) { r0[w] = p0; r1[w] = p1; r2[w] = p2; }
    __syncthreads();
    if (tid == 0) {
        out[0] = b_ho[0] + r0[0] + r0[1] + r0[2] + r0[3];
        out[1] = b_ho[1] + r1[0] + r1[1] + r1[2] + r1[3];
        out[2] = b_ho[2] + r2[0] + r2[1] + r2[2] + r2[3];
    }
}

// ---------------- fallback (R2 kernel, used only if ws too small) ----------------
#define ROWS_PER_BLK 32
#define UNITS_PER_BLK 8
#define KW 64

__global__ __launch_bounds__(NTHR, 2)
void bilstm_fallback(const float* __restrict__ x,
                     const float* __restrict__ Wih_f, const float* __restrict__ Whh_f,
                     const float* __restrict__ bih_f, const float* __restrict__ bhh_f,
                     const float* __restrict__ Wih_b, const float* __restrict__ Whh_b,
                     const float* __restrict__ bih_b, const float* __restrict__ bhh_b,
                     u64* hpack)
{
    const int tid = threadIdx.x;
    const int blk = blockIdx.x;
    const int dir = blk >> 7;
    const int lb  = blk & 127;
    const int u0  = lb * UNITS_PER_BLK;
    const int r_local = tid >> 4;
    const int kc  = tid & 15;
    const int q   = r_local >> 3;
    const int uu  = r_local & 7;
    const int grow = q * HID + u0 + uu;

    const float* Wih = dir ? Wih_b : Wih_f;
    const float* Whh = dir ? Whh_b : Whh_f;
    const float* bih = dir ? bih_b : bih_f;
    const float* bhh = dir ? bhh_b : bhh_f;
    u64* hp = hpack + (size_t)dir * 2 * HID;

    __shared__ float lds_h[16 * PAD];
    __shared__ float lds_x[16 * PAD];
    __shared__ float lds_g[ROWS_PER_BLK];
    __shared__ float lds_bias[ROWS_PER_BLK];

    float wih[KW], whh[KW];
    {
        const float* pih = Wih + (size_t)grow * ISZ + kc * KW;
        const float* phh = Whh + (size_t)grow * HID + kc * KW;
        #pragma unroll
        for (int j = 0; j < KW; j += 4) {
            float4 a = *(const float4*)(pih + j);
            wih[j] = a.x; wih[j+1] = a.y; wih[j+2] = a.z; wih[j+3] = a.w;
            float4 b4 = *(const float4*)(phh + j);
            whh[j] = b4.x; whh[j+1] = b4.y; whh[j+2] = b4.z; whh[j+3] = b4.w;
        }
    }
    #pragma unroll
    for (int j = 0; j < KW; ++j) {
        asm volatile("" : "+v"(wih[j]));
        asm volatile("" : "+v"(whh[j]));
    }
    if (tid < ROWS_PER_BLK) {
        int qq = tid >> 3, u2 = tid & 7;
        int gr = qq * HID + u0 + u2;
        lds_bias[tid] = bih[gr] + bhh[gr];
    }
    float c_state = 0.0f;
    {
        int xrow = dir ? (T_SEQ - 1) : 0;
        const float* xp = x + (size_t)xrow * ISZ;
        int i0 = tid * 2;
        float2 v = *(const float2*)(xp + i0);
        *(float2*)&lds_x[(i0 >> 6) * PAD + (i0 & 63)] = v;
    }
    __syncthreads();
    float xacc = 0.0f;
    {
        const float* lx = lds_x + kc * PAD;
        #pragma unroll
        for (int j = 0; j < KW; j += 4) {
            float4 v = *(const float4*)(lx + j);
            xacc += wih[j]*v.x + wih[j+1]*v.y + wih[j+2]*v.z + wih[j+3]*v.w;
        }
    }
    bool dead = false;
    for (int t = 0; t < T_SEQ; ++t) {
        float pre = xacc;
        if (t > 0) {
            u64* src = hp + ((size_t)((t - 1) & 1)) * HID;
            const int pi = tid * 2;
            u64 e0 = 0, e1 = 0;
            if (!dead) {
                int sp = 0;
                while (((e0 = __hip_atomic_load(src + pi, __ATOMIC_RELAXED,
                                                __HIP_MEMORY_SCOPE_AGENT)) >> 32) != (unsigned)t) {
                    if (++sp > (1 << 21)) { dead = true; break; }
                }
                sp = 0;
                if (!dead) {
                    while (((e1 = __hip_atomic_load(src + pi + 1, __ATOMIC_RELAXED,
                                                    __HIP_MEMORY_SCOPE_AGENT)) >> 32) != (unsigned)t) {
                        if (++sp > (1 << 21)) { dead = true; break; }
                    }
                }
            }
            lds_h[(pi >> 6) * PAD + (pi & 63)] = __uint_as_float((unsigned)(e0 & 0xffffffffu));
            lds_h[((pi + 1) >> 6) * PAD + ((pi + 1) & 63)] = __uint_as_float((unsigned)(e1 & 0xffffffffu));
            __syncthreads();
            const float* lh = lds_h + kc * PAD;
            #pragma unroll
            for (int j = 0; j < KW; j += 4) {
                float4 v = *(const float4*)(lh + j);
                pre += whh[j]*v.x + whh[j+1]*v.y + whh[j+2]*v.z + whh[j+3]*v.w;
            }
        }
        pre += __shfl_xor(pre, 1);
        pre += __shfl_xor(pre, 2);
        pre += __shfl_xor(pre, 4);
        pre += __shfl_xor(pre, 8);
        if (kc == 0) lds_g[r_local] = pre + lds_bias[r_local];
        __syncthreads();
        if (tid < UNITS_PER_BLK) {
            float gi = lds_g[0 * 8 + tid];
            float gf = lds_g[1 * 8 + tid];
            float gg = lds_g[2 * 8 + tid];
            float go = lds_g[3 * 8 + tid];
            float si = fast_sigmoid(gi);
            float sf = fast_sigmoid(gf);
            float so = fast_sigmoid(go);
            float tg = fast_tanh(gg);
            c_state = sf * c_state + si * tg;
            float hval = so * fast_tanh(c_state);
            u64 pk = ((u64)(unsigned)(t + 1) << 32) | (u64)__float_as_uint(hval);
            __hip_atomic_store(hp + ((size_t)(t & 1)) * HID + u0 + tid, pk,
                               __ATOMIC_RELAXED, __HIP_MEMORY_SCOPE_AGENT);
        }
        if (t + 1 < T_SEQ) {
            int xrow = dir ? (T_SEQ - 2 - t) : (t + 1);
            const float* xp = x + (size_t)xrow * ISZ;
            int i0 = tid * 2;
            float2 v = *(const float2*)(xp + i0);
            *(float2*)&lds_x[(i0 >> 6) * PAD + (i0 & 63)] = v;
            __syncthreads();
            xacc = 0.0f;
            const float* lx = lds_x + kc * PAD;
            #pragma unroll
            for (int j = 0; j < KW; j += 4) {
                float4 v4 = *(const float4*)(lx + j);
                xacc += wih[j]*v4.x + wih[j+1]*v4.y + wih[j+2]*v4.z + wih[j+3]*v4.w;
            }
        }
    }
}

extern "C" void kernel_launch(void* const* d_in, const int* in_sizes, int n_in,
                              void* d_out, int out_size, void* d_ws, size_t ws_size,
                              hipStream_t stream) {
    const float* x     = (const float*)d_in[0];
    const float* Wih_f = (const float*)d_in[1];
    const float* Whh_f = (const float*)d_in[2];
    const float* bih_f = (const float*)d_in[3];
    const float* bhh_f = (const float*)d_in[4];
    const float* Wih_b = (const float*)d_in[5];
    const float* Whh_b = (const float*)d_in[6];
    const float* bih_b = (const float*)d_in[7];
    const float* bhh_b = (const float*)d_in[8];
    const float* W_ho  = (const float*)d_in[9];
    const float* b_ho  = (const float*)d_in[10];

    u64* hpack = (u64*)d_ws;                              // 32 KB
    float* xg = (float*)((char*)d_ws + 32768);            // 128 MB
    const size_t need = 32768 + (size_t)2 * T_SEQ * G4H * sizeof(float);

    hipMemsetAsync(d_ws, 0, 2 * 2 * HID * sizeof(u64), stream);

    if (ws_size >= need) {
        dim3 gg(G4H / GN, T_SEQ / GM, 2);
        xproj_gemm<<<gg, 256, 0, stream>>>(x, Wih_f, bih_f, bhh_f,
                                           Wih_b, bih_b, bhh_b, xg);
        bilstm_rec<<<NB_TOT, NTHR, 0, stream>>>(xg, Whh_f, Whh_b, hpack);
    } else {
        bilstm_fallback<<<NB_TOT, NTHR, 0, stream>>>(
            x, Wih_f, Whh_f, bih_f, bhh_f, Wih_b, Whh_b, bih_b, bhh_b, hpack);
    }
    head_kernel<<<1, 256, 0, stream>>>(W_ho, b_ho, hpack, (float*)d_out);
}